// Round 1
// 128.963 us; speedup vs baseline: 1.0126x; 1.0126x over previous
//
#include <hip/hip_runtime.h>

// SupConLoss, B=8192, D=128, T=5.0
// v2: algebraic decomposition. Inner loop keeps only (row-max, fixed-scale Z):
//   e = 2^(raw*invT*log2e - 40), Z += e, m = max(m, raw)
// A_i = (f_i . G[lbl_i] - ||f_i||^2) * invT  (class sums G),  cnt_i = hist[lbl_i]-1.
// term_i = (A - cnt*m)/cnt - log(1e-12 + Z * exp(40*ln2 - m)),  loss = -(1/B) sum term.

#define BN 8192
#define DK 128
#define INV_T 0.2f
#define C1F 0.28853901f     // INV_T * log2(e)
#define C40F 27.7258872f    // 40 * ln(2)

#define CHUNKS 32
#define CCOLS (BN / CHUNKS)     // 256 cols per chunk
#define RPB 256                 // rows per block = 4 waves * 64
#define RT 4                    // 16-row MFMA tiles per wave
#define NJT (CCOLS / 16)        // 16

#define NCLS 100
#define PB 128                  // prep blocks
#define PROWS (BN / PB)         // 64 rows per prep block

// workspace layout (bytes)
#define OFF_FB    0                                   // 2 MB bf16 features
#define OFF_DIAG  (2 * 1024 * 1024)                   // 32 KB f32 ||f||^2
#define OFF_PART  (OFF_DIAG + 32768)                  // 2 MB float2 [CHUNKS][BN]
#define OFF_GP    (OFF_PART + 2 * 1024 * 1024)        // 6.25 MB G partials [PB][100][128]
#define OFF_HISTP (OFF_GP + PB * NCLS * DK * 4)       // 50 KB hist partials [PB][100]
#define OFF_G     (OFF_HISTP + PB * NCLS * 4)         // 50 KB class sums
#define OFF_HIST  (OFF_G + NCLS * DK * 4)             // hist
#define OFF_BSUM  (OFF_HIST + 512)                    // block sums
#define OFF_CTR   (OFF_BSUM + 128)                    // arrival counter

typedef __attribute__((ext_vector_type(8))) short bf16x8;   // 8 bf16 = 4 VGPRs
typedef __attribute__((ext_vector_type(4))) float f32x4;

__device__ __forceinline__ unsigned short f2bf(float f) {
    unsigned u = __builtin_bit_cast(unsigned, f);
    u += 0x7fffu + ((u >> 16) & 1u);
    return (unsigned short)(u >> 16);
}

__device__ __forceinline__ float fexp2(float x) {
#if __has_builtin(__builtin_amdgcn_exp2f)
    return __builtin_amdgcn_exp2f(x);
#else
    float r; asm("v_exp_f32 %0, %1" : "=v"(r) : "v"(x)); return r;
#endif
}

// prep: cast to bf16, diag = ||f||^2, per-block label hist + class-sum partials
__global__ __launch_bounds__(256) void prep_kernel(const float* __restrict__ F,
                                                   const int* __restrict__ labels,
                                                   unsigned short* __restrict__ Fb,
                                                   float* __restrict__ diag,
                                                   float* __restrict__ Gp,
                                                   int* __restrict__ histp,
                                                   unsigned int* __restrict__ ctr) {
    const int t  = threadIdx.x;
    const int b  = blockIdx.x;
    const int r0 = b * PROWS;

    if (b == 0 && t == 0) *ctr = 0u;   // re-arm finalize's last-block counter

    // cast: 64 rows = 2048 float4 per block
    const float4* F4  = (const float4*)F + (size_t)b * (PROWS * DK / 4);
    ushort4*      Fb4 = (ushort4*)Fb + (size_t)b * (PROWS * DK / 4);
#pragma unroll
    for (int k = 0; k < PROWS * DK / 4 / 256; ++k) {   // 8
        float4 v = F4[k * 256 + t];
        ushort4 o;
        o.x = f2bf(v.x); o.y = f2bf(v.y); o.z = f2bf(v.z); o.w = f2bf(v.w);
        Fb4[k * 256 + t] = o;
    }

    // diag: 4 threads per row
    {
        const int row = r0 + (t >> 2);
        const int q   = t & 3;
        const float4* rp = (const float4*)(F + (size_t)row * DK) + q * 8;
        float s = 0.f;
#pragma unroll
        for (int k = 0; k < 8; ++k) {
            float4 v = rp[k];
            s += v.x * v.x + v.y * v.y + v.z * v.z + v.w * v.w;
        }
        s += __shfl_xor(s, 1);
        s += __shfl_xor(s, 2);
        if (q == 0) diag[row] = s;
    }

    __shared__ int   lh[NCLS];
    __shared__ float gl[NCLS][DK];    // 51.2 KB
    float* glf = (float*)gl;
    if (t < NCLS) lh[t] = 0;
#pragma unroll
    for (int k = 0; k < NCLS * DK / 256; ++k) glf[k * 256 + t] = 0.f;   // 50
    __syncthreads();

    if (t < PROWS) atomicAdd(&lh[labels[r0 + t]], 1);

    // class-sum partial: threads 0..127 own one column each; rows serial (uniform label)
    if (t < DK) {
        for (int rr = 0; rr < PROWS; ++rr) {
            const int row = r0 + rr;
            const int c   = labels[row];
            gl[c][t] += F[(size_t)row * DK + t];
        }
    }
    __syncthreads();

    if (t < NCLS) histp[b * NCLS + t] = lh[t];
#pragma unroll
    for (int k = 0; k < NCLS * DK / 256; ++k) {   // 50
        const int idx = k * 256 + t;
        Gp[(size_t)b * (NCLS * DK) + idx] = glf[idx];
    }
}

template <bool DIAGBLK>
__device__ __forceinline__ void supcon_rows(const short* __restrict__ Fb,
                                            float2* __restrict__ part,
                                            int bx, int by) {
    const int t    = threadIdx.x;
    const int wave = t >> 6, lane = t & 63;
    const int quad = lane >> 4, l16 = lane & 15;
    const int rowBase = bx * RPB + wave * (RT * 16);
    const int colBase = by * CCOLS;

    // A fragments: 64 rows x K=128 resident in registers for the whole chunk
    bf16x8 a[RT][4];
#pragma unroll
    for (int rt = 0; rt < RT; ++rt)
#pragma unroll
        for (int kt = 0; kt < 4; ++kt)
            a[rt][kt] = *(const bf16x8*)(Fb + (size_t)(rowBase + rt * 16 + l16) * DK
                                            + kt * 32 + quad * 8);

    float mr[RT][4], Zs[RT][4];
#pragma unroll
    for (int rt = 0; rt < RT; ++rt)
#pragma unroll
        for (int r = 0; r < 4; ++r) { mr[rt][r] = -__builtin_inff(); Zs[rt][r] = 0.f; }

    const short* bp = Fb + (size_t)(colBase + l16) * DK + quad * 8;
    bf16x8 bc[4], bn[4];
#pragma unroll
    for (int kt = 0; kt < 4; ++kt) bc[kt] = *(const bf16x8*)(bp + kt * 32);

    auto STEP = [&](const bf16x8 (&bb)[4], int jtc) {
        const int j0 = colBase + jtc * 16;
#pragma unroll
        for (int rt = 0; rt < RT; ++rt) {
            f32x4 acc = {0.f, 0.f, 0.f, 0.f};
#pragma unroll
            for (int kt = 0; kt < 4; ++kt)
                acc = __builtin_amdgcn_mfma_f32_16x16x32_bf16(a[rt][kt], bb[kt], acc, 0, 0, 0);
            float e[4];
#pragma unroll
            for (int r = 0; r < 4; ++r) {
                const float raw = acc[r];
                mr[rt][r] = fmaxf(mr[rt][r], raw);            // row max (incl diag, as ref)
                e[r] = fexp2(fmaf(raw, C1F, -40.0f));          // fixed-scale exp
            }
            if (DIAGBLK) {
                const int irow0 = rowBase + rt * 16 + quad * 4;
#pragma unroll
                for (int r = 0; r < 4; ++r)
                    if (j0 + l16 == irow0 + r) e[r] = 0.f;     // Z excludes diagonal
            }
#pragma unroll
            for (int r = 0; r < 4; ++r) Zs[rt][r] += e[r];
        }
    };

    for (int jt = 0; jt < NJT; jt += 2) {
        bp += 16 * DK;
#pragma unroll
        for (int kt = 0; kt < 4; ++kt) bn[kt] = *(const bf16x8*)(bp + kt * 32);  // prefetch jt+1
        STEP(bc, jt);
        if (jt + 2 < NJT) {
            bp += 16 * DK;
#pragma unroll
            for (int kt = 0; kt < 4; ++kt) bc[kt] = *(const bf16x8*)(bp + kt * 32); // prefetch jt+2
        }
        STEP(bn, jt + 1);
    }

    // merge across the 16 lanes holding different columns of the same rows
#pragma unroll
    for (int rt = 0; rt < RT; ++rt)
#pragma unroll
        for (int r = 0; r < 4; ++r) {
            float mm = mr[rt][r], zz = Zs[rt][r];
#pragma unroll
            for (int h = 1; h < 16; h <<= 1) {
                mm = fmaxf(mm, __shfl_xor(mm, h));
                zz += __shfl_xor(zz, h);
            }
            if (l16 == 0)
                part[(size_t)by * BN + rowBase + rt * 16 + quad * 4 + r] =
                    make_float2(mm, zz);
        }
}

__global__ __launch_bounds__(256, 3) void supcon_main(const short* __restrict__ Fb,
                                                      float2* __restrict__ part,
                                                      const float* __restrict__ Gp,
                                                      const int* __restrict__ histp,
                                                      float* __restrict__ G,
                                                      int* __restrict__ hist) {
    if (blockIdx.y == CHUNKS) {   // 32 rider blocks: reduce G/hist partials
        const int base = blockIdx.x * 256 + threadIdx.x;
        for (int idx = base; idx < NCLS * DK + NCLS; idx += BN) {
            if (idx < NCLS * DK) {
                float s = 0.f;
#pragma unroll 8
                for (int p = 0; p < PB; ++p) s += Gp[(size_t)p * (NCLS * DK) + idx];
                G[idx] = s;
            } else {
                const int c = idx - NCLS * DK;
                int s = 0;
#pragma unroll 8
                for (int p = 0; p < PB; ++p) s += histp[p * NCLS + c];
                hist[c] = s;
            }
        }
        return;
    }
    if (blockIdx.x == blockIdx.y) supcon_rows<true >(Fb, part, blockIdx.x, blockIdx.y);
    else                          supcon_rows<false>(Fb, part, blockIdx.x, blockIdx.y);
}

__global__ __launch_bounds__(256) void supcon_finalize(const float* __restrict__ F,
                                                       const int* __restrict__ labels,
                                                       const float2* __restrict__ part,
                                                       const float* __restrict__ diag,
                                                       const float* __restrict__ G,
                                                       const int* __restrict__ hist,
                                                       float* __restrict__ bsums,
                                                       unsigned int* __restrict__ ctr,
                                                       float* __restrict__ out) {
    const int t = threadIdx.x;
    const int i = blockIdx.x * 256 + t;

    float mraw = -__builtin_inff(), Zm = 0.f;
#pragma unroll 8
    for (int c = 0; c < CHUNKS; ++c) {
        const float2 p = part[(size_t)c * BN + i];
        mraw = fmaxf(mraw, p.x);
        Zm += p.y;
    }
    const int   lbl = labels[i];
    const float cnt = (float)(hist[lbl] - 1);

    const float4* fr = (const float4*)(F + (size_t)i * DK);
    const float4* gr = (const float4*)(G + lbl * DK);
    float dot = 0.f;
#pragma unroll 8
    for (int k = 0; k < DK / 4; ++k) {
        const float4 av = fr[k], gv = gr[k];
        dot += av.x * gv.x + av.y * gv.y + av.z * gv.z + av.w * gv.w;
    }

    const float m = mraw * INV_T;
    const float A = (dot - diag[i]) * INV_T;
    float term = 0.f;
    if (cnt > 0.5f)
        term = (A - cnt * m) / cnt - __logf(1e-12f + Zm * __expf(C40F - m));

    float sum = term;
#pragma unroll
    for (int h = 1; h < 64; h <<= 1) sum += __shfl_xor(sum, h);
    __shared__ float ss[4];
    if ((t & 63) == 0) ss[t >> 6] = sum;
    __syncthreads();
    if (t == 0) {
        bsums[blockIdx.x] = ss[0] + ss[1] + ss[2] + ss[3];
        __threadfence();
        const unsigned old = atomicAdd(ctr, 1u);
        if (old == (BN / 256) - 1) {   // last block folds the final reduction
            __threadfence();
            float tot = 0.f;
            const volatile float* vb = bsums;
            for (int c = 0; c < BN / 256; ++c) tot += vb[c];
            out[0] = -tot * (1.0f / BN);
        }
    }
}

extern "C" void kernel_launch(void* const* d_in, const int* in_sizes, int n_in,
                              void* d_out, int out_size, void* d_ws, size_t ws_size,
                              hipStream_t stream) {
    const float* F      = (const float*)d_in[0];
    const int*   labels = (const int*)d_in[1];
    // d_in[2] (fac_label) is a no-op in the reference math.
    float* out = (float*)d_out;
    char*  ws  = (char*)d_ws;

    unsigned short* Fb    = (unsigned short*)(ws + OFF_FB);
    float*          diag  = (float*)(ws + OFF_DIAG);
    float2*         part  = (float2*)(ws + OFF_PART);
    float*          Gp    = (float*)(ws + OFF_GP);
    int*            histp = (int*)(ws + OFF_HISTP);
    float*          G     = (float*)(ws + OFF_G);
    int*            hist  = (int*)(ws + OFF_HIST);
    float*          bsums = (float*)(ws + OFF_BSUM);
    unsigned int*   ctr   = (unsigned int*)(ws + OFF_CTR);

    prep_kernel<<<PB, 256, 0, stream>>>(F, labels, Fb, diag, Gp, histp, ctr);
    supcon_main<<<dim3(BN / RPB, CHUNKS + 1), 256, 0, stream>>>((const short*)Fb, part,
                                                                Gp, histp, G, hist);
    supcon_finalize<<<BN / 256, 256, 0, stream>>>(F, labels, part, diag, G, hist,
                                                  bsums, ctr, out);
}

// Round 2
// 116.733 us; speedup vs baseline: 1.1187x; 1.1048x over previous
//
#include <hip/hip_runtime.h>

// SupConLoss, B=8192, D=128, T=5.0
// v3: v2's algebraic decomposition + LDS-shared B tiles.
//   - B tile (16 cols x 128 k, 4 KB) staged once per block via global_load_lds,
//     double-buffered, XOR-swizzled (linear LDS dest + inverse-swizzled global src).
//   - diag ||f||^2 folded into finalize (free alongside the G-dot).
// Inner loop per element: fmax + fma + exp2 + add.
//   e = 2^(raw*invT*log2e - 40), Z += e, m = max(m, raw)
// A_i = (f_i . G[lbl_i] - ||f_i||^2)*invT, cnt_i = hist[lbl_i]-1
// term_i = (A - cnt*m)/cnt - log(1e-12 + Z * exp(40*ln2 - m)); loss = -(1/B) sum term

#define BN 8192
#define DK 128
#define INV_T 0.2f
#define C1F 0.28853901f     // INV_T * log2(e)
#define C40F 27.7258872f    // 40 * ln(2)

#define CHUNKS 32
#define CCOLS (BN / CHUNKS)     // 256 cols per chunk
#define RPB 256                 // rows per block = 4 waves * 64
#define RT 4                    // 16-row MFMA tiles per wave
#define NJT (CCOLS / 16)        // 16

#define NCLS 100
#define PB 128                  // prep blocks
#define PROWS (BN / PB)         // 64 rows per prep block

// workspace layout (bytes)
#define OFF_FB    0                                   // 2 MB bf16 features
#define OFF_PART  (2 * 1024 * 1024)                   // 2 MB float2 [CHUNKS][BN]
#define OFF_GP    (OFF_PART + 2 * 1024 * 1024)        // 6.55 MB G partials [PB][100][128]
#define OFF_HISTP (OFF_GP + PB * NCLS * DK * 4)       // 51 KB hist partials
#define OFF_G     (OFF_HISTP + PB * NCLS * 4)         // class sums
#define OFF_HIST  (OFF_G + NCLS * DK * 4)             // hist
#define OFF_BSUM  (OFF_HIST + 512)                    // block sums
#define OFF_CTR   (OFF_BSUM + 256)                    // arrival counter

typedef __attribute__((ext_vector_type(8))) short bf16x8;   // 8 bf16 = 4 VGPRs
typedef __attribute__((ext_vector_type(4))) float f32x4;

__device__ __forceinline__ unsigned short f2bf(float f) {
    unsigned u = __builtin_bit_cast(unsigned, f);
    u += 0x7fffu + ((u >> 16) & 1u);
    return (unsigned short)(u >> 16);
}

__device__ __forceinline__ float fexp2(float x) {
#if __has_builtin(__builtin_amdgcn_exp2f)
    return __builtin_amdgcn_exp2f(x);
#else
    float r; asm("v_exp_f32 %0, %1" : "=v"(r) : "v"(x)); return r;
#endif
}

__device__ __forceinline__ void load_lds16(const void* g, void* l) {
    __builtin_amdgcn_global_load_lds(
        (const __attribute__((address_space(1))) unsigned int*)g,
        (__attribute__((address_space(3))) unsigned int*)l, 16, 0, 0);
}

// prep: cast to bf16, per-block label hist + class-sum partials
__global__ __launch_bounds__(256) void prep_kernel(const float* __restrict__ F,
                                                   const int* __restrict__ labels,
                                                   unsigned short* __restrict__ Fb,
                                                   float* __restrict__ Gp,
                                                   int* __restrict__ histp,
                                                   unsigned int* __restrict__ ctr) {
    const int t  = threadIdx.x;
    const int b  = blockIdx.x;
    const int r0 = b * PROWS;

    if (b == 0 && t == 0) *ctr = 0u;   // re-arm finalize's last-block counter

    // cast: 64 rows = 2048 float4 per block
    const float4* F4  = (const float4*)F + (size_t)b * (PROWS * DK / 4);
    ushort4*      Fb4 = (ushort4*)Fb + (size_t)b * (PROWS * DK / 4);
#pragma unroll
    for (int k = 0; k < PROWS * DK / 4 / 256; ++k) {   // 8
        float4 v = F4[k * 256 + t];
        ushort4 o;
        o.x = f2bf(v.x); o.y = f2bf(v.y); o.z = f2bf(v.z); o.w = f2bf(v.w);
        Fb4[k * 256 + t] = o;
    }

    __shared__ int   lh[NCLS];
    __shared__ float gl[NCLS][DK];    // 51.2 KB
    float* glf = (float*)gl;
    if (t < NCLS) lh[t] = 0;
#pragma unroll
    for (int k = 0; k < NCLS * DK / 256; ++k) glf[k * 256 + t] = 0.f;   // 50
    __syncthreads();

    if (t < PROWS) atomicAdd(&lh[labels[r0 + t]], 1);

    // class-sum partial: threads 0..127 own one column each; rows serial
    if (t < DK) {
        for (int rr = 0; rr < PROWS; ++rr) {
            const int row = r0 + rr;
            const int c   = labels[row];
            gl[c][t] += F[(size_t)row * DK + t];
        }
    }
    __syncthreads();

    if (t < NCLS) histp[b * NCLS + t] = lh[t];
#pragma unroll
    for (int k = 0; k < NCLS * DK / 256; ++k) {   // 50
        const int idx = k * 256 + t;
        Gp[(size_t)b * (NCLS * DK) + idx] = glf[idx];
    }
}

template <bool DIAGBLK>
__device__ __forceinline__ void supcon_rows(const short* __restrict__ Fb,
                                            float2* __restrict__ part,
                                            int bx, int by, char* smem) {
    const int t    = threadIdx.x;
    const int wave = t >> 6, lane = t & 63;
    const int quad = lane >> 4, l16 = lane & 15;
    const int rowBase = bx * RPB + wave * (RT * 16);
    const int colBase = by * CCOLS;

    // A fragments: 64 rows x K=128 resident in registers for the whole chunk
    bf16x8 a[RT][4];
#pragma unroll
    for (int rt = 0; rt < RT; ++rt)
#pragma unroll
        for (int kt = 0; kt < 4; ++kt)
            a[rt][kt] = *(const bf16x8*)(Fb + (size_t)(rowBase + rt * 16 + l16) * DK
                                            + kt * 32 + quad * 8);

    float mr[RT][4], Zs[RT][4];
#pragma unroll
    for (int rt = 0; rt < RT; ++rt)
#pragma unroll
        for (int r = 0; r < 4; ++r) { mr[rt][r] = -__builtin_inff(); Zs[rt][r] = 0.f; }

    // staging: per-lane inverse-swizzled global source, linear LDS dest.
    // tile byte L holds global byte (L&~255) | ((L&255) ^ (((L>>8)&7)<<4))
    const int  L    = wave * 1024 + lane * 16;
    const int  sw   = (L & ~255) | ((L & 255) ^ ((L >> 4) & 0x70));
    const char* tile0 = (const char*)(Fb + (size_t)colBase * DK);   // 4 KB per jt tile
    char*       dst0  = smem + wave * 1024;

    // swizzled read offsets (col r=l16, field f=kt*64+quad*16):
    int roff[4];
#pragma unroll
    for (int kt = 0; kt < 4; ++kt)
        roff[kt] = l16 * 256 + ((kt * 64 + quad * 16) ^ ((l16 & 7) << 4));

    auto STAGE = [&](int bufoff, int jt) {
        load_lds16(tile0 + (size_t)jt * 4096 + sw, dst0 + bufoff);
    };

    auto COMPUTE = [&](int bufoff, int jt) {
        bf16x8 bb[4];
#pragma unroll
        for (int kt = 0; kt < 4; ++kt)
            bb[kt] = *(const bf16x8*)(smem + bufoff + roff[kt]);
        const int j0 = colBase + jt * 16;
#pragma unroll
        for (int rt = 0; rt < RT; ++rt) {
            f32x4 acc = {0.f, 0.f, 0.f, 0.f};
#pragma unroll
            for (int kt = 0; kt < 4; ++kt)
                acc = __builtin_amdgcn_mfma_f32_16x16x32_bf16(a[rt][kt], bb[kt], acc, 0, 0, 0);
#pragma unroll
            for (int r = 0; r < 4; ++r) {
                const float raw = acc[r];
                mr[rt][r] = fmaxf(mr[rt][r], raw);            // row max (incl diag, as ref)
                float e = fexp2(fmaf(raw, C1F, -40.0f));       // fixed-scale exp
                if (DIAGBLK) {
                    const int irow0 = rowBase + rt * 16 + quad * 4;
                    if (j0 + l16 == irow0 + r) e = 0.f;        // Z excludes diagonal
                }
                Zs[rt][r] += e;
            }
        }
    };

    STAGE(0, 0);
    __syncthreads();                     // compiler drains vmcnt before s_barrier
    for (int jt = 0; jt < NJT; jt += 2) {
        STAGE(4096, jt + 1);             // issue next tile early (T14)
        COMPUTE(0, jt);
        __syncthreads();
        if (jt + 2 < NJT) STAGE(0, jt + 2);
        COMPUTE(4096, jt + 1);
        __syncthreads();
    }

    // merge across the 16 lanes holding different columns of the same rows
#pragma unroll
    for (int rt = 0; rt < RT; ++rt)
#pragma unroll
        for (int r = 0; r < 4; ++r) {
            float mm = mr[rt][r], zz = Zs[rt][r];
#pragma unroll
            for (int h = 1; h < 16; h <<= 1) {
                mm = fmaxf(mm, __shfl_xor(mm, h));
                zz += __shfl_xor(zz, h);
            }
            if (l16 == 0)
                part[(size_t)by * BN + rowBase + rt * 16 + quad * 4 + r] =
                    make_float2(mm, zz);
        }
}

__global__ __launch_bounds__(256) void supcon_main(const short* __restrict__ Fb,
                                                   float2* __restrict__ part,
                                                   const float* __restrict__ Gp,
                                                   const int* __restrict__ histp,
                                                   float* __restrict__ G,
                                                   int* __restrict__ hist) {
    __shared__ alignas(16) char smem[8192];
    if (blockIdx.y == CHUNKS) {   // 32 rider blocks: reduce G/hist partials
        const int base = blockIdx.x * 256 + threadIdx.x;
        for (int idx = base; idx < NCLS * DK + NCLS; idx += BN) {
            if (idx < NCLS * DK) {
                float s = 0.f;
#pragma unroll 8
                for (int p = 0; p < PB; ++p) s += Gp[(size_t)p * (NCLS * DK) + idx];
                G[idx] = s;
            } else {
                const int c = idx - NCLS * DK;
                int s = 0;
#pragma unroll 8
                for (int p = 0; p < PB; ++p) s += histp[p * NCLS + c];
                hist[c] = s;
            }
        }
        return;
    }
    if (blockIdx.x == blockIdx.y) supcon_rows<true >(Fb, part, blockIdx.x, blockIdx.y, smem);
    else                          supcon_rows<false>(Fb, part, blockIdx.x, blockIdx.y, smem);
}

__global__ __launch_bounds__(256) void supcon_finalize(const float* __restrict__ F,
                                                       const int* __restrict__ labels,
                                                       const float2* __restrict__ part,
                                                       const float* __restrict__ G,
                                                       const int* __restrict__ hist,
                                                       float* __restrict__ bsums,
                                                       unsigned int* __restrict__ ctr,
                                                       float* __restrict__ out) {
    const int t = threadIdx.x;
    const int i = blockIdx.x * 256 + t;

    float mraw = -__builtin_inff(), Zm = 0.f;
#pragma unroll 8
    for (int c = 0; c < CHUNKS; ++c) {
        const float2 p = part[(size_t)c * BN + i];
        mraw = fmaxf(mraw, p.x);
        Zm += p.y;
    }
    const int   lbl = labels[i];
    const float cnt = (float)(hist[lbl] - 1);

    const float4* fr = (const float4*)(F + (size_t)i * DK);
    const float4* gr = (const float4*)(G + lbl * DK);
    float dot = 0.f, nrm = 0.f;
#pragma unroll 8
    for (int k = 0; k < DK / 4; ++k) {
        const float4 av = fr[k], gv = gr[k];
        dot += av.x * gv.x + av.y * gv.y + av.z * gv.z + av.w * gv.w;
        nrm += av.x * av.x + av.y * av.y + av.z * av.z + av.w * av.w;
    }

    const float m = mraw * INV_T;
    const float A = (dot - nrm) * INV_T;
    float term = 0.f;
    if (cnt > 0.5f)
        term = (A - cnt * m) / cnt - __logf(1e-12f + Zm * __expf(C40F - m));

    float sum = term;
#pragma unroll
    for (int h = 1; h < 64; h <<= 1) sum += __shfl_xor(sum, h);
    __shared__ float ss[4];
    if ((t & 63) == 0) ss[t >> 6] = sum;
    __syncthreads();
    if (t == 0) {
        bsums[blockIdx.x] = ss[0] + ss[1] + ss[2] + ss[3];
        __threadfence();
        const unsigned old = atomicAdd(ctr, 1u);
        if (old == (BN / 256) - 1) {   // last block folds the final reduction
            __threadfence();
            float tot = 0.f;
            const volatile float* vb = bsums;
            for (int c = 0; c < BN / 256; ++c) tot += vb[c];
            out[0] = -tot * (1.0f / BN);
        }
    }
}

extern "C" void kernel_launch(void* const* d_in, const int* in_sizes, int n_in,
                              void* d_out, int out_size, void* d_ws, size_t ws_size,
                              hipStream_t stream) {
    const float* F      = (const float*)d_in[0];
    const int*   labels = (const int*)d_in[1];
    // d_in[2] (fac_label) is a no-op in the reference math.
    float* out = (float*)d_out;
    char*  ws  = (char*)d_ws;

    unsigned short* Fb    = (unsigned short*)(ws + OFF_FB);
    float2*         part  = (float2*)(ws + OFF_PART);
    float*          Gp    = (float*)(ws + OFF_GP);
    int*            histp = (int*)(ws + OFF_HISTP);
    float*          G     = (float*)(ws + OFF_G);
    int*            hist  = (int*)(ws + OFF_HIST);
    float*          bsums = (float*)(ws + OFF_BSUM);
    unsigned int*   ctr   = (unsigned int*)(ws + OFF_CTR);

    prep_kernel<<<PB, 256, 0, stream>>>(F, labels, Fb, Gp, histp, ctr);
    supcon_main<<<dim3(BN / RPB, CHUNKS + 1), 256, 0, stream>>>((const short*)Fb, part,
                                                                Gp, histp, G, hist);
    supcon_finalize<<<BN / 256, 256, 0, stream>>>(F, labels, part, G, hist,
                                                  bsums, ctr, out);
}